// Round 1
// baseline (1610.070 us; speedup 1.0000x reference)
//
#include <hip/hip_runtime.h>

#define N 8192
#define DIM 256
#define QB 32           // queries per block
#define NWAVES 8
#define CB (NWAVES*16)  // candidates per iteration = 128
#define LK 33           // keep 33 smallest (need 32nd and 33rd NN)

typedef short bf16x8 __attribute__((ext_vector_type(8)));
typedef float f32x4 __attribute__((ext_vector_type(4)));

static __device__ inline unsigned short f2bf(float f) {
    unsigned int u = __float_as_uint(f);
    unsigned int r = (u + 0x7fffu + ((u >> 16) & 1u)) >> 16;
    return (unsigned short)r;
}

// ---------------- Kernel A: norms (fp32) + bf16 cast ----------------
__global__ __launch_bounds__(64) void prep_kernel(const float* __restrict__ feat,
                                                  unsigned short* __restrict__ fb,
                                                  float* __restrict__ norms) {
    int row = blockIdx.x;
    int lane = threadIdx.x;  // 64 lanes, 4 floats each = 256 dims
    float4 v = reinterpret_cast<const float4*>(feat + (size_t)row * DIM)[lane];
    float ss = v.x * v.x + v.y * v.y + v.z * v.z + v.w * v.w;
    #pragma unroll
    for (int off = 32; off > 0; off >>= 1) ss += __shfl_xor(ss, off);
    if (lane == 0) norms[row] = ss;
    ushort4 b;
    b.x = f2bf(v.x); b.y = f2bf(v.y); b.z = f2bf(v.z); b.w = f2bf(v.w);
    reinterpret_cast<ushort4*>(fb + (size_t)row * DIM)[lane] = b;
}

// ---------------- Kernel B: gram MFMA + top-33 selection ----------------
__device__ inline void rescan_max(const float* ld, const int* li,
                                  float& md, int& mi, int& mp) {
    md = -3.0e38f; mi = -1; mp = 0;
    for (int t = 0; t < LK; t++) {
        float d = ld[t]; int ix = li[t];
        if (d > md || (d == md && ix > mi)) { md = d; mi = ix; mp = t; }
    }
}

__global__ __launch_bounds__(NWAVES * 64, 1) void knn_kernel(
    const unsigned short* __restrict__ fb, const float* __restrict__ norms,
    float* __restrict__ kd32sq, float* __restrict__ kd33sq, int* __restrict__ knn) {
    __shared__ float qn[QB];
    __shared__ float thresh[QB];
    __shared__ float list_d[QB][LK];
    __shared__ int   list_i[QB][LK];
    __shared__ int   lcnt[QB];
    __shared__ float buf_d[QB][CB];
    __shared__ int   buf_i[QB][CB];
    __shared__ int   bcnt[QB];

    int tid = threadIdx.x;
    int w = tid >> 6;
    int lane = tid & 63;
    int qbase = blockIdx.x * QB;

    if (tid < QB) {
        qn[tid] = norms[qbase + tid];
        thresh[tid] = 3.0e38f;
        lcnt[tid] = 0;
        bcnt[tid] = 0;
    }
    __syncthreads();

    // A fragments: queries held in registers for the whole kernel.
    // mfma_f32_16x16x32_bf16: lane supplies row=(lane&15), k = kstep*32 + (lane>>4)*8 + [0..8)
    int koff = (lane >> 4) * 8;
    int arow = qbase + (lane & 15);
    bf16x8 aq[2][8];
    #pragma unroll
    for (int rt = 0; rt < 2; rt++)
        #pragma unroll
        for (int ks = 0; ks < 8; ks++)
            aq[rt][ks] = *reinterpret_cast<const bf16x8*>(
                fb + (size_t)(arow + rt * 16) * DIM + ks * 32 + koff);

    for (int it = 0; it < N / CB; it++) {
        int cw = it * CB + w * 16;
        int crow = cw + (lane & 15);
        bf16x8 bq[8];
        #pragma unroll
        for (int ks = 0; ks < 8; ks++)
            bq[ks] = *reinterpret_cast<const bf16x8*>(
                fb + (size_t)crow * DIM + ks * 32 + koff);

        f32x4 acc0 = {0.f, 0.f, 0.f, 0.f};
        f32x4 acc1 = {0.f, 0.f, 0.f, 0.f};
        #pragma unroll
        for (int ks = 0; ks < 8; ks++) {
            acc0 = __builtin_amdgcn_mfma_f32_16x16x32_bf16(aq[0][ks], bq[ks], acc0, 0, 0, 0);
            acc1 = __builtin_amdgcn_mfma_f32_16x16x32_bf16(aq[1][ks], bq[ks], acc1, 0, 0, 0);
        }

        float cn = norms[crow];
        // C/D layout (verified m89): col = lane&15 (candidate), row = (lane>>4)*4 + j (query)
        #pragma unroll
        for (int rt = 0; rt < 2; rt++) {
            f32x4 acc = rt ? acc1 : acc0;
            int qrow0 = rt * 16 + (lane >> 4) * 4;
            #pragma unroll
            for (int j = 0; j < 4; j++) {
                int ql = qrow0 + j;
                float d2 = qn[ql] + cn - 2.0f * acc[j];
                if (crow != qbase + ql && d2 <= thresh[ql]) {
                    int p = atomicAdd(&bcnt[ql], 1);
                    buf_d[ql][p] = d2;
                    buf_i[ql][p] = crow;
                }
            }
        }
        __syncthreads();

        // merge phase: one thread per query, replace-max (no sorting needed)
        if (tid < QB) {
            int q = tid;
            int n = bcnt[q];
            if (n > 0) {
                bcnt[q] = 0;
                int c = lcnt[q];
                float m1d = 3.0e38f; int m1i = 0x7fffffff, m1p = 0;
                if (c == LK) rescan_max(&list_d[q][0], &list_i[q][0], m1d, m1i, m1p);
                for (int b = 0; b < n; b++) {
                    float d = buf_d[q][b]; int ix = buf_i[q][b];
                    if (c < LK) {
                        list_d[q][c] = d; list_i[q][c] = ix; c++;
                        if (c == LK) rescan_max(&list_d[q][0], &list_i[q][0], m1d, m1i, m1p);
                    } else if (d < m1d || (d == m1d && ix < m1i)) {
                        list_d[q][m1p] = d; list_i[q][m1p] = ix;
                        rescan_max(&list_d[q][0], &list_i[q][0], m1d, m1i, m1p);
                    }
                }
                lcnt[q] = c;
                thresh[q] = (c == LK) ? m1d : 3.0e38f;
            }
        }
        __syncthreads();
    }

    // epilogue: max of 33 = kd33 (the 33rd NN), 2nd max = kd32, other 32 = NN set
    if (tid < QB) {
        int q = tid;
        int g = qbase + q;
        float m1d; int m1i, m1p;
        rescan_max(&list_d[q][0], &list_i[q][0], m1d, m1i, m1p);
        float m2d = -3.0e38f; int m2i = -1;
        for (int t = 0; t < LK; t++) {
            if (t == m1p) continue;
            float d = list_d[q][t]; int ix = list_i[q][t];
            if (d > m2d || (d == m2d && ix > m2i)) { m2d = d; m2i = ix; }
        }
        kd33sq[g] = m1d;
        kd32sq[g] = m2d;
        int o = 0;
        for (int t = 0; t < LK; t++) {
            if (t == m1p) continue;
            knn[(size_t)g * 32 + o] = list_i[q][t];
            o++;
        }
    }
}

// ---------------- Kernel C: scores ----------------
__global__ __launch_bounds__(256) void scores_kernel(
    const float* __restrict__ kd32sq, const float* __restrict__ kd33sq,
    const int* __restrict__ knn, float* __restrict__ out) {
    int i = blockIdx.x * blockDim.x + threadIdx.x;
    float num = sqrtf(fmaxf(kd33sq[i], 0.0f));
    float s = 0.0f;
    #pragma unroll
    for (int t = 0; t < 32; t++) {
        int j = knn[(size_t)i * 32 + t];
        int m = j - (j > i);  // reference uses reduced index directly into a_full_d rows
        float den = sqrtf(fmaxf(kd32sq[m], 0.0f));
        s += num / den;
    }
    s *= (1.0f / 32.0f);
    if (isnan(s)) s = 1000.0f;
    else if (isinf(s)) s = (s > 0.0f) ? 1000.0f : 0.0f;
    out[i] = s;
}

extern "C" void kernel_launch(void* const* d_in, const int* in_sizes, int n_in,
                              void* d_out, int out_size, void* d_ws, size_t ws_size,
                              hipStream_t stream) {
    (void)in_sizes; (void)n_in; (void)out_size; (void)ws_size;
    const float* feat = (const float*)d_in[0];

    char* ws = (char*)d_ws;
    unsigned short* fb = (unsigned short*)ws;                       // 4 MB bf16 features
    float* norms = (float*)(ws + (size_t)4 * 1024 * 1024);          // 32 KB
    float* kd32 = (float*)(ws + (size_t)4 * 1024 * 1024 + 32768);
    float* kd33 = (float*)(ws + (size_t)4 * 1024 * 1024 + 65536);
    int* knn = (int*)(ws + (size_t)4 * 1024 * 1024 + 98304);        // 1 MB

    prep_kernel<<<N, 64, 0, stream>>>(feat, fb, norms);
    knn_kernel<<<N / QB, NWAVES * 64, 0, stream>>>(fb, norms, kd32, kd33, knn);
    scores_kernel<<<N / 256, 256, 0, stream>>>(kd32, kd33, knn, (float*)d_out);
}

// Round 2
// 312.738 us; speedup vs baseline: 5.1483x; 5.1483x over previous
//
#include <hip/hip_runtime.h>

#define N 8192
#define DIM 256
#define QB 32           // queries per block
#define NWAVES 8
#define CB (NWAVES*16)  // candidates per iteration = 128
#define NIT (N / CB)    // 64
#define LK 33           // need 32nd and 33rd NN
#define NBIN 512        // histogram bins over d^2 in [0, 1024), width 2
#define BUFCAP 128      // pass-2 per-query candidate buffer

typedef short bf16x8 __attribute__((ext_vector_type(8)));
typedef float f32x4 __attribute__((ext_vector_type(4)));

static __device__ inline unsigned short f2bf(float f) {
    unsigned int u = __float_as_uint(f);
    unsigned int r = (u + 0x7fffu + ((u >> 16) & 1u)) >> 16;
    return (unsigned short)r;
}

// identical d^2 arithmetic in both passes (bit-exact across kernels)
static __device__ inline float dist2(float qn_plus_cn, float acc) {
    return __builtin_fmaf(-2.0f, acc, qn_plus_cn);
}

// ---------------- Kernel A: norms (fp32) + bf16 cast ----------------
__global__ __launch_bounds__(64) void prep_kernel(const float* __restrict__ feat,
                                                  unsigned short* __restrict__ fb,
                                                  float* __restrict__ norms) {
    int row = blockIdx.x;
    int lane = threadIdx.x;
    float4 v = reinterpret_cast<const float4*>(feat + (size_t)row * DIM)[lane];
    float ss = v.x * v.x + v.y * v.y + v.z * v.z + v.w * v.w;
    #pragma unroll
    for (int off = 32; off > 0; off >>= 1) ss += __shfl_xor(ss, off);
    if (lane == 0) norms[row] = ss;
    ushort4 b;
    b.x = f2bf(v.x); b.y = f2bf(v.y); b.z = f2bf(v.z); b.w = f2bf(v.w);
    reinterpret_cast<ushort4*>(fb + (size_t)row * DIM)[lane] = b;
}

// ---------------- Pass 1: per-query d^2 histogram -> threshold ----------------
__global__ __launch_bounds__(NWAVES * 64) void hist_kernel(
    const unsigned short* __restrict__ fb, const float* __restrict__ norms,
    float* __restrict__ tq) {
    __shared__ unsigned int hist[QB][NBIN + 1];  // +1 pad: conflict-free scan
    __shared__ float qn[QB];

    int tid = threadIdx.x;
    int w = tid >> 6;
    int lane = tid & 63;
    int qbase = blockIdx.x * QB;

    for (int i = tid; i < QB * (NBIN + 1); i += NWAVES * 64)
        (&hist[0][0])[i] = 0u;
    if (tid < QB) qn[tid] = norms[qbase + tid];
    __syncthreads();

    // A fragments: 2 row-tiles of 16 queries, resident in registers
    int koff = (lane >> 4) * 8;
    int arow = qbase + (lane & 15);
    bf16x8 aq[2][8];
    #pragma unroll
    for (int rt = 0; rt < 2; rt++)
        #pragma unroll
        for (int ks = 0; ks < 8; ks++)
            aq[rt][ks] = *reinterpret_cast<const bf16x8*>(
                fb + (size_t)(arow + rt * 16) * DIM + ks * 32 + koff);

    // hoist per-lane query constants out of the loop
    float qnr[2][4];
    unsigned int* hrow[2][4];
    int qgl[2][4];
    #pragma unroll
    for (int rt = 0; rt < 2; rt++)
        #pragma unroll
        for (int j = 0; j < 4; j++) {
            int ql = rt * 16 + (lane >> 4) * 4 + j;
            qnr[rt][j] = qn[ql];
            hrow[rt][j] = &hist[ql][0];
            qgl[rt][j] = qbase + ql;
        }

    int cbase = w * 16 + (lane & 15);
    bf16x8 bq[8];
    #pragma unroll
    for (int ks = 0; ks < 8; ks++)
        bq[ks] = *reinterpret_cast<const bf16x8*>(
            fb + (size_t)cbase * DIM + ks * 32 + koff);
    float cn = norms[cbase];

    for (int it = 0; it < NIT; it++) {
        int crow = it * CB + cbase;
        bf16x8 bn[8];
        float cnn = 0.0f;
        if (it + 1 < NIT) {
            int nrow = crow + CB;
            #pragma unroll
            for (int ks = 0; ks < 8; ks++)
                bn[ks] = *reinterpret_cast<const bf16x8*>(
                    fb + (size_t)nrow * DIM + ks * 32 + koff);
            cnn = norms[nrow];
        }

        f32x4 acc0 = {0.f, 0.f, 0.f, 0.f};
        f32x4 acc1 = {0.f, 0.f, 0.f, 0.f};
        #pragma unroll
        for (int ks = 0; ks < 8; ks++) {
            acc0 = __builtin_amdgcn_mfma_f32_16x16x32_bf16(aq[0][ks], bq[ks], acc0, 0, 0, 0);
            acc1 = __builtin_amdgcn_mfma_f32_16x16x32_bf16(aq[1][ks], bq[ks], acc1, 0, 0, 0);
        }

        #pragma unroll
        for (int rt = 0; rt < 2; rt++) {
            f32x4 acc = rt ? acc1 : acc0;
            #pragma unroll
            for (int j = 0; j < 4; j++) {
                float d2 = dist2(qnr[rt][j] + cn, acc[j]);
                if (crow != qgl[rt][j]) {
                    int b = (int)(d2 * 0.5f);
                    b = b < 0 ? 0 : (b > NBIN - 1 ? NBIN - 1 : b);
                    atomicAdd(&hrow[rt][j][b], 1u);
                }
            }
        }

        #pragma unroll
        for (int ks = 0; ks < 8; ks++) bq[ks] = bn[ks];
        cn = cnn;
    }
    __syncthreads();

    if (tid < QB) {
        unsigned int cum = 0;
        int bstar = NBIN - 1;
        for (int b = 0; b < NBIN; b++) {
            cum += hist[tid][b];
            if (cum >= LK) { bstar = b; break; }
        }
        tq[qbase + tid] = (float)(bstar + 1) * 2.0f;  // upper edge of 33rd-NN bin
    }
}

// ---------------- Pass 2: collect d^2 < T, exact top-33 select ----------------
__device__ inline void rescan_max(const float* ld, const int* li,
                                  float& md, int& mi, int& mp) {
    md = -3.0e38f; mi = -1; mp = 0;
    for (int t = 0; t < LK; t++) {
        float d = ld[t]; int ix = li[t];
        if (d > md || (d == md && ix > mi)) { md = d; mi = ix; mp = t; }
    }
}

__global__ __launch_bounds__(NWAVES * 64) void collect_kernel(
    const unsigned short* __restrict__ fb, const float* __restrict__ norms,
    const float* __restrict__ tq,
    float* __restrict__ kd32sq, float* __restrict__ kd33sq, int* __restrict__ knn) {
    __shared__ float qn[QB];
    __shared__ float Tsh[QB];
    __shared__ float buf_d[QB][BUFCAP];
    __shared__ int   buf_i[QB][BUFCAP];
    __shared__ int   bcnt[QB];
    __shared__ float list_d[QB][LK];
    __shared__ int   list_i[QB][LK];

    int tid = threadIdx.x;
    int w = tid >> 6;
    int lane = tid & 63;
    int qbase = blockIdx.x * QB;

    if (tid < QB) {
        qn[tid] = norms[qbase + tid];
        Tsh[tid] = tq[qbase + tid];
        bcnt[tid] = 0;
    }
    __syncthreads();

    int koff = (lane >> 4) * 8;
    int arow = qbase + (lane & 15);
    bf16x8 aq[2][8];
    #pragma unroll
    for (int rt = 0; rt < 2; rt++)
        #pragma unroll
        for (int ks = 0; ks < 8; ks++)
            aq[rt][ks] = *reinterpret_cast<const bf16x8*>(
                fb + (size_t)(arow + rt * 16) * DIM + ks * 32 + koff);

    float qnr[2][4], Tr[2][4];
    int qln[2][4], qgl[2][4];
    #pragma unroll
    for (int rt = 0; rt < 2; rt++)
        #pragma unroll
        for (int j = 0; j < 4; j++) {
            int ql = rt * 16 + (lane >> 4) * 4 + j;
            qnr[rt][j] = qn[ql];
            Tr[rt][j] = Tsh[ql];
            qln[rt][j] = ql;
            qgl[rt][j] = qbase + ql;
        }

    int cbase = w * 16 + (lane & 15);
    bf16x8 bq[8];
    #pragma unroll
    for (int ks = 0; ks < 8; ks++)
        bq[ks] = *reinterpret_cast<const bf16x8*>(
            fb + (size_t)cbase * DIM + ks * 32 + koff);
    float cn = norms[cbase];

    for (int it = 0; it < NIT; it++) {
        int crow = it * CB + cbase;
        bf16x8 bn[8];
        float cnn = 0.0f;
        if (it + 1 < NIT) {
            int nrow = crow + CB;
            #pragma unroll
            for (int ks = 0; ks < 8; ks++)
                bn[ks] = *reinterpret_cast<const bf16x8*>(
                    fb + (size_t)nrow * DIM + ks * 32 + koff);
            cnn = norms[nrow];
        }

        f32x4 acc0 = {0.f, 0.f, 0.f, 0.f};
        f32x4 acc1 = {0.f, 0.f, 0.f, 0.f};
        #pragma unroll
        for (int ks = 0; ks < 8; ks++) {
            acc0 = __builtin_amdgcn_mfma_f32_16x16x32_bf16(aq[0][ks], bq[ks], acc0, 0, 0, 0);
            acc1 = __builtin_amdgcn_mfma_f32_16x16x32_bf16(aq[1][ks], bq[ks], acc1, 0, 0, 0);
        }

        #pragma unroll
        for (int rt = 0; rt < 2; rt++) {
            f32x4 acc = rt ? acc1 : acc0;
            #pragma unroll
            for (int j = 0; j < 4; j++) {
                float d2 = dist2(qnr[rt][j] + cn, acc[j]);
                if (crow != qgl[rt][j] && d2 < Tr[rt][j]) {
                    int ql = qln[rt][j];
                    int p = atomicAdd(&bcnt[ql], 1);
                    if (p < BUFCAP) { buf_d[ql][p] = d2; buf_i[ql][p] = crow; }
                }
            }
        }

        #pragma unroll
        for (int ks = 0; ks < 8; ks++) bq[ks] = bn[ks];
        cn = cnn;
    }
    __syncthreads();

    // exact top-33 over the ~37 collected candidates; one thread per query
    if (tid < QB) {
        int q = tid;
        int g = qbase + q;
        int n = bcnt[q]; if (n > BUFCAP) n = BUFCAP;
        int c = 0;
        float m1d = 3.0e38f; int m1i = 0x7fffffff, m1p = 0;
        for (int b = 0; b < n; b++) {
            float d = buf_d[q][b]; int ix = buf_i[q][b];
            if (c < LK) {
                list_d[q][c] = d; list_i[q][c] = ix; c++;
                if (c == LK) rescan_max(&list_d[q][0], &list_i[q][0], m1d, m1i, m1p);
            } else if (d < m1d || (d == m1d && ix < m1i)) {
                list_d[q][m1p] = d; list_i[q][m1p] = ix;
                rescan_max(&list_d[q][0], &list_i[q][0], m1d, m1i, m1p);
            }
        }
        // max of 33 = 33rd NN (kd33), 2nd max = 32nd NN (kd32), rest = NN set
        rescan_max(&list_d[q][0], &list_i[q][0], m1d, m1i, m1p);
        float m2d = -3.0e38f; int m2i = -1;
        for (int t = 0; t < LK; t++) {
            if (t == m1p) continue;
            float d = list_d[q][t]; int ix = list_i[q][t];
            if (d > m2d || (d == m2d && ix > m2i)) { m2d = d; m2i = ix; }
        }
        kd33sq[g] = m1d;
        kd32sq[g] = m2d;
        int o = 0;
        for (int t = 0; t < LK; t++) {
            if (t == m1p) continue;
            knn[(size_t)g * 32 + o] = list_i[q][t];
            o++;
        }
    }
}

// ---------------- Kernel C: scores ----------------
__global__ __launch_bounds__(256) void scores_kernel(
    const float* __restrict__ kd32sq, const float* __restrict__ kd33sq,
    const int* __restrict__ knn, float* __restrict__ out) {
    int i = blockIdx.x * blockDim.x + threadIdx.x;
    float num = sqrtf(fmaxf(kd33sq[i], 0.0f));
    float s = 0.0f;
    #pragma unroll
    for (int t = 0; t < 32; t++) {
        int j = knn[(size_t)i * 32 + t];
        int m = j - (j > i);  // reference indexes a_full_d rows with reduced index
        float den = sqrtf(fmaxf(kd32sq[m], 0.0f));
        s += num / den;
    }
    s *= (1.0f / 32.0f);
    if (isnan(s)) s = 1000.0f;
    else if (isinf(s)) s = (s > 0.0f) ? 1000.0f : 0.0f;
    out[i] = s;
}

extern "C" void kernel_launch(void* const* d_in, const int* in_sizes, int n_in,
                              void* d_out, int out_size, void* d_ws, size_t ws_size,
                              hipStream_t stream) {
    (void)in_sizes; (void)n_in; (void)out_size; (void)ws_size;
    const float* feat = (const float*)d_in[0];

    char* ws = (char*)d_ws;
    unsigned short* fb = (unsigned short*)ws;                        // 4 MB bf16 features
    size_t off = (size_t)4 * 1024 * 1024;
    float* norms = (float*)(ws + off); off += 32768;
    float* kd32  = (float*)(ws + off); off += 32768;
    float* kd33  = (float*)(ws + off); off += 32768;
    float* tqv   = (float*)(ws + off); off += 32768;
    int*   knn   = (int*)(ws + off);                                 // 1 MB

    prep_kernel<<<N, 64, 0, stream>>>(feat, fb, norms);
    hist_kernel<<<N / QB, NWAVES * 64, 0, stream>>>(fb, norms, tqv);
    collect_kernel<<<N / QB, NWAVES * 64, 0, stream>>>(fb, norms, tqv, kd32, kd33, knn);
    scores_kernel<<<N / 256, 256, 0, stream>>>(kd32, kd33, knn, (float*)d_out);
}